// Round 16
// baseline (84.791 us; speedup 1.0000x reference)
//
#include <hip/hip_runtime.h>

// Chamfer distance, B=16, N=M=4096, D=3.
// dist(i,j) = n1 + n2 - 2*x1.x2 as ONE bf16 MFMA per 32x32 tile (norms folded
// into padded K slots, hi/lo bf16 split => exact-grade; absmax 0.0 since R1).
// R20: single-dispatch merge done RIGHT. R18's failure was plain stores
// (dirty in producer XCD's L2, threadfence insufficient). G16's sanctioned
// path: device-scope ATOMICS (stores/loads at the coherent LLC point).
//  - R16 body verbatim (81.2 us best; inner loop proven at its floor by R17
//    probes: 7us MFMA + ~8.6us fold VALU, pipelining/stagger both null).
//  - epilogue: __hip_atomic_store (AGENT) into rowpart planes.
//  - arrival counter: __device__ g_cnt (zero at load; launch-relative target
//    arithmetic -> no reset dispatch, robust to rocprof replays).
//  - last 16 arrivals elect (one per batch), spin till all 512 (all blocks
//    co-resident at 2/CU -> no deadlock), reduce via __hip_atomic_load with
//    arithmetic bit-identical to R16's reduce_rows.
// Saves the second dispatch + ~6us launch boundary. Pre-commit: absmax!=0 ->
// revert to R19; neutral -> ROOFLINE.

typedef __attribute__((ext_vector_type(8))) __bf16 bf16x8;
typedef __attribute__((ext_vector_type(16))) float f32x16;

#define PTS 4096
#define NB 16

__device__ unsigned g_cnt = 0;  // monotone across launches; launch-relative

__device__ __forceinline__ unsigned f2bf(float f) {
  unsigned u = __float_as_uint(f);
  return (u + 0x7FFFu + ((u >> 16) & 1u)) >> 16;  // RNE bf16 bits
}
__device__ __forceinline__ float bf2f(unsigned s) {
  return __uint_as_float(s << 16);
}
__device__ __forceinline__ unsigned pk(unsigned lo, unsigned hi) {
  return (lo & 0xFFFFu) | (hi << 16);
}

// ---- fused: 512 threads (8 waves). Block builds its 64-tile (2048-col)
// B-panel in LDS, 8 waves stream it (2 row-tiles each = 512 rows/block).
// grid = (64,8): x = (dir,b,ch) -> XCD = x%8 ; y = row-group.
// 512 blocks = 2/CU (64KB LDS) -> all co-resident.
__global__ __launch_bounds__(512, 2) void chamfer_all(
    const float* __restrict__ x1, const float* __restrict__ x2,
    float* __restrict__ rowpart, float* __restrict__ out) {
  const int s  = blockIdx.x;           // 64 slices: (dir, batch, colhalf)
  const int d  = s & 1;
  const int b  = (s >> 1) & (NB - 1);
  const int ch = (s >> 5) & 1;
  const int rg = blockIdx.y;           // 8 row-groups of 512 rows

  const int tid  = threadIdx.x;
  const int lane = tid & 63;
  const int half = lane >> 5;          // K-half this lane supplies to MFMA
  const int l31  = lane & 31;
  const int wave = tid >> 6;           // 0..7

  __shared__ uint4 lds[4096];          // 64 tiles x 1 KB = 64 KB

  // --- build B-panel in LDS from raw col-side points ---
  // B k-vec: w0=[Hx Hy Hz Lx Ly Lz Hx Hy] w1=[Hz nh nl 1 1 0 0 0], H,L = -2q.
  const float* Q = d ? x1 : x2;        // col side = opposite of row side
  const int cbase = b * PTS + ch * 2048;
#pragma unroll
  for (int k = 0; k < 4; ++k) {
    const int j = tid + k * 512;       // 2048 panel points
    const float* q = Q + (size_t)(cbase + j) * 3;
    const float x = q[0], y = q[1], z = q[2];
    const float sx = -2.f * x, sy = -2.f * y, sz = -2.f * z;
    const unsigned Hx = f2bf(sx), Hy = f2bf(sy), Hz = f2bf(sz);
    const unsigned Lx = f2bf(sx - bf2f(Hx));
    const unsigned Ly = f2bf(sy - bf2f(Hy));
    const unsigned Lz = f2bf(sz - bf2f(Hz));
    const float n = fmaf(x, x, fmaf(y, y, z * z));
    const unsigned nh = f2bf(n), nl = f2bf(n - bf2f(nh));
    const unsigned one = 0x3F80u;
    uint4 w0, w1;
    w0.x = pk(Hx, Hy); w0.y = pk(Hz, Lx); w0.z = pk(Ly, Lz); w0.w = pk(Hx, Hy);
    w1.x = pk(Hz, nh); w1.y = pk(nl, one); w1.z = pk(one, 0u); w1.w = 0u;
    lds[(j >> 5) * 64 + (j & 31)]      = w0;  // half 0 (k 0..7)
    lds[(j >> 5) * 64 + 32 + (j & 31)] = w1;  // half 1 (k 8..15)
  }

  // --- build A fragments from raw points (row tiles t0, t0+1) ---
  // A k-vec: w0=[hx hy hz hx hy hz lx ly]  w1=[lz 1 1 nh nl 0 0 0]
  const float* P = d ? x2 : x1;
  const int t0 = rg * 16 + wave * 2;
  bf16x8 af[2];
#pragma unroll
  for (int rr = 0; rr < 2; ++rr) {
    const int r = (t0 + rr) * 32 + l31;
    const float* p = P + (size_t)(b * PTS + r) * 3;
    const float x = p[0], y = p[1], zc = p[2];
    const unsigned hx = f2bf(x), hy = f2bf(y), hz = f2bf(zc);
    const unsigned lx = f2bf(x - bf2f(hx));
    const unsigned ly = f2bf(y - bf2f(hy));
    const unsigned lz = f2bf(zc - bf2f(hz));
    const float n = fmaf(x, x, fmaf(y, y, zc * zc));
    const unsigned nh = f2bf(n), nl = f2bf(n - bf2f(nh));
    const unsigned one = 0x3F80u;
    uint4 w0, w1;
    w0.x = pk(hx, hy); w0.y = pk(hz, hx); w0.z = pk(hy, hz); w0.w = pk(lx, ly);
    w1.x = pk(lz, one); w1.y = pk(one, nh); w1.z = pk(nl, 0u); w1.w = 0u;
    uint4 w;
    w.x = half ? w1.x : w0.x; w.y = half ? w1.y : w0.y;
    w.z = half ? w1.z : w0.z; w.w = half ? w1.w : w0.w;
    af[rr] = *(const bf16x8*)&w;
  }
  const bf16x8 af0 = af[0], af1 = af[1];

  f32x16 zero;
#pragma unroll
  for (int e = 0; e < 16; ++e) zero[e] = 0.f;

  float rm0[16], rm1[16];
#pragma unroll
  for (int e = 0; e < 16; ++e) { rm0[e] = 3.0e38f; rm1[e] = 3.0e38f; }

  __syncthreads();  // panel staged (read-only afterwards: no more barriers)

  // --- stream 64 tiles from LDS; 4-slot ring, 2 reads in flight ---
  const uint4* tp = &lds[half * 32 + l31];  // tile stride = 64 uint4
  bf16x8 buf[4];
  buf[0] = *(const bf16x8*)&tp[0];
  buf[1] = *(const bf16x8*)&tp[64];

#pragma unroll 2
  for (int g = 0; g < 32; ++g) {
    const int cur = (g & 1) * 2;
    const int nxt = ((g + 1) & 1) * 2;
    const int pf  = ((g + 1) & 31) * 2;  // wrap: last prefetch redundant, safe
    buf[nxt]     = *(const bf16x8*)&tp[pf * 64];
    buf[nxt + 1] = *(const bf16x8*)&tp[(pf + 1) * 64];
    const bf16x8 b0 = buf[cur], b1 = buf[cur + 1];
    const f32x16 a00 =
        __builtin_amdgcn_mfma_f32_32x32x16_bf16(af0, b0, zero, 0, 0, 0);
    const f32x16 a01 =
        __builtin_amdgcn_mfma_f32_32x32x16_bf16(af0, b1, zero, 0, 0, 0);
#pragma unroll
    for (int e = 0; e < 16; ++e)
      rm0[e] = fminf(fminf(a00[e], a01[e]), rm0[e]);  // v_min3_f32
    const f32x16 a10 =
        __builtin_amdgcn_mfma_f32_32x32x16_bf16(af1, b0, zero, 0, 0, 0);
    const f32x16 a11 =
        __builtin_amdgcn_mfma_f32_32x32x16_bf16(af1, b1, zero, 0, 0, 0);
#pragma unroll
    for (int e = 0; e < 16; ++e)
      rm1[e] = fminf(fminf(a10[e], a11[e]), rm1[e]);
  }

  // --- per-row min, device-scope ATOMIC store (LLC-coherent cross-XCD) ---
  // C/D layout: col = lane&31, row_local = (e&3) + 8*(e>>2) + 4*half.
  unsigned* rbase =
      (unsigned*)(rowpart + ((size_t)((ch * 2 + d) * NB + b)) * PTS + t0 * 32);
#pragma unroll
  for (int e = 0; e < 16; ++e) {
    float v = rm0[e];
    v = fminf(v, __shfl_xor(v, 1));
    v = fminf(v, __shfl_xor(v, 2));
    v = fminf(v, __shfl_xor(v, 4));
    v = fminf(v, __shfl_xor(v, 8));
    v = fminf(v, __shfl_xor(v, 16));
    if (l31 == e) {
      const int rl = (e & 3) + 8 * (e >> 2) + 4 * half;
      __hip_atomic_store(rbase + rl, __float_as_uint(fmaxf(v, 0.f)),
                         __ATOMIC_RELAXED, __HIP_MEMORY_SCOPE_AGENT);
    }
  }
#pragma unroll
  for (int e = 0; e < 16; ++e) {
    float v = rm1[e];
    v = fminf(v, __shfl_xor(v, 1));
    v = fminf(v, __shfl_xor(v, 2));
    v = fminf(v, __shfl_xor(v, 4));
    v = fminf(v, __shfl_xor(v, 8));
    v = fminf(v, __shfl_xor(v, 16));
    if (l31 == e) {
      const int rl = 32 + (e & 3) + 8 * (e >> 2) + 4 * half;
      __hip_atomic_store(rbase + rl, __float_as_uint(fmaxf(v, 0.f)),
                         __ATOMIC_RELAXED, __HIP_MEMORY_SCOPE_AGENT);
    }
  }

  // --- arrival count; last NB arrivals elect (one per batch) ---
  __syncthreads();  // all waves' atomic stores issued & drained (vmcnt)
  __shared__ unsigned s_old;
  if (tid == 0)
    s_old = __hip_atomic_fetch_add(&g_cnt, 1u, __ATOMIC_ACQ_REL,
                                   __HIP_MEMORY_SCOPE_AGENT);
  __syncthreads();
  const unsigned old = s_old;
  const unsigned idx = old & 511u;     // position within this launch's 512
  if (idx < 512u - NB) return;
  const int bb = (int)(idx - (512u - NB));
  const unsigned target = (old - idx) + 512u;
  if (tid == 0) {
    while (__hip_atomic_load(&g_cnt, __ATOMIC_ACQUIRE,
                             __HIP_MEMORY_SCOPE_AGENT) < target)
      __builtin_amdgcn_s_sleep(1);
  }
  __syncthreads();

  // --- reduce batch bb (atomic loads; arithmetic == R16 reduce_rows) ---
  unsigned* q0 = (unsigned*)(rowpart + (size_t)(0 * NB + bb) * PTS);  // ch0,d0
  unsigned* q1 = (unsigned*)(rowpart + (size_t)(1 * NB + bb) * PTS);  // ch0,d1
  unsigned* q2 = (unsigned*)(rowpart + (size_t)(2 * NB + bb) * PTS);  // ch1,d0
  unsigned* q3 = (unsigned*)(rowpart + (size_t)(3 * NB + bb) * PTS);  // ch1,d1
  float ssum = 0.f;
  for (int i = tid; i < PTS; i += 512) {
    const float a0 = __uint_as_float(__hip_atomic_load(
        q0 + i, __ATOMIC_RELAXED, __HIP_MEMORY_SCOPE_AGENT));
    const float a1 = __uint_as_float(__hip_atomic_load(
        q1 + i, __ATOMIC_RELAXED, __HIP_MEMORY_SCOPE_AGENT));
    const float a2 = __uint_as_float(__hip_atomic_load(
        q2 + i, __ATOMIC_RELAXED, __HIP_MEMORY_SCOPE_AGENT));
    const float a3 = __uint_as_float(__hip_atomic_load(
        q3 + i, __ATOMIC_RELAXED, __HIP_MEMORY_SCOPE_AGENT));
    ssum += fminf(a0, a2) + fminf(a1, a3);
  }
  ssum += __shfl_xor(ssum, 1);
  ssum += __shfl_xor(ssum, 2);
  ssum += __shfl_xor(ssum, 4);
  ssum += __shfl_xor(ssum, 8);
  ssum += __shfl_xor(ssum, 16);
  ssum += __shfl_xor(ssum, 32);
  __shared__ float facc[8];
  if ((tid & 63) == 0) facc[wave] = ssum;
  __syncthreads();
  if (tid == 0) {
    float t = 0.f;
#pragma unroll
    for (int w = 0; w < 8; ++w) t += facc[w];
    out[bb] = t * (1.f / PTS);
  }
}

extern "C" void kernel_launch(void* const* d_in, const int* in_sizes, int n_in,
                              void* d_out, int out_size, void* d_ws,
                              size_t ws_size, hipStream_t stream) {
  const float* x1 = (const float*)d_in[0];
  const float* x2 = (const float*)d_in[1];
  float* out = (float*)d_out;

  float* rowpart = (float*)d_ws;  // 4*NB*PTS floats = 1 MB, fully overwritten

  dim3 grid(64, 8);  // x = (dir,b,ch) slice -> XCD = x%8 ; y = row-group
  chamfer_all<<<grid, 512, 0, stream>>>(x1, x2, rowpart, out);
}

// Round 17
// 81.341 us; speedup vs baseline: 1.0424x; 1.0424x over previous
//
#include <hip/hip_runtime.h>

// Chamfer distance, B=16, N=M=4096, D=3.
// dist(i,j) = n1 + n2 - 2*x1.x2 as ONE bf16 MFMA per 32x32 tile (norms folded
// into padded K slots, hi/lo bf16 split => exact-grade; absmax 0.0 since R1).
// R21: FINAL revert to R19 (81.2 us, best verified). R20's atomic-handoff
// single-dispatch was correct but slower (84.8: LLC atomic reads + serialized
// spin tail > one saved launch boundary). Session ledger:
//  - inner loop at structural floor (R17 probes: 7us MFMA floor + ~8.6us
//    accvgpr/fold VALU; deferred-fold pipeline NULL; wave stagger NULL)
//  - occupancy capped at 4 waves/SIMD by unified VGPR+AGPR footprint
//    (R15 spilled at cap 64; R12 grid-split neutral; R14/R16 = max residency)
//  - fused row+col one-pass spills unconditionally (R5-R8)
//  - single-dispatch merges: plain-store incorrect (R18, cross-XCD); atomic
//    correct but slower (R20)
// Remaining budget: 41us harness fill + ~18.5us main + ~3us reduce + ~18us
// launch boundaries. This is the floor of this structure on this harness.

typedef __attribute__((ext_vector_type(8))) __bf16 bf16x8;
typedef __attribute__((ext_vector_type(16))) float f32x16;

#define PTS 4096
#define NB 16

__device__ __forceinline__ unsigned f2bf(float f) {
  unsigned u = __float_as_uint(f);
  return (u + 0x7FFFu + ((u >> 16) & 1u)) >> 16;  // RNE bf16 bits
}
__device__ __forceinline__ float bf2f(unsigned s) {
  return __uint_as_float(s << 16);
}
__device__ __forceinline__ unsigned pk(unsigned lo, unsigned hi) {
  return (lo & 0xFFFFu) | (hi << 16);
}

// ---- main: 512 threads (8 waves). Block builds its 64-tile (2048-col)
// B-panel in LDS from raw points, then all 8 waves stream it (2 row-tiles
// per wave = 512 rows/block). grid.x = 64 slices (dir,b,ch) -> XCD = x%8 ;
// grid.y = 8 row-groups. 512 blocks = 2/CU (64KB LDS), 4 waves/SIMD (reg cap).
__global__ __launch_bounds__(512, 2) void chamfer_main(
    const float* __restrict__ x1, const float* __restrict__ x2,
    float* __restrict__ rowpart) {
  const int s  = blockIdx.x;           // 64 slices: (dir, batch, colhalf)
  const int d  = s & 1;
  const int b  = (s >> 1) & (NB - 1);
  const int ch = (s >> 5) & 1;
  const int rg = blockIdx.y;           // 8 row-groups of 512 rows

  const int tid  = threadIdx.x;
  const int lane = tid & 63;
  const int half = lane >> 5;          // K-half this lane supplies to MFMA
  const int l31  = lane & 31;
  const int wave = tid >> 6;           // 0..7

  __shared__ uint4 lds[4096];          // 64 tiles x 1 KB = 64 KB

  // --- build B-panel in LDS from raw col-side points ---
  // B k-vec: w0=[Hx Hy Hz Lx Ly Lz Hx Hy] w1=[Hz nh nl 1 1 0 0 0], H,L = -2q.
  const float* Q = d ? x1 : x2;        // col side = opposite of row side
  const int cbase = b * PTS + ch * 2048;
#pragma unroll
  for (int k = 0; k < 4; ++k) {
    const int j = tid + k * 512;       // 2048 panel points
    const float* q = Q + (size_t)(cbase + j) * 3;
    const float x = q[0], y = q[1], z = q[2];
    const float sx = -2.f * x, sy = -2.f * y, sz = -2.f * z;
    const unsigned Hx = f2bf(sx), Hy = f2bf(sy), Hz = f2bf(sz);
    const unsigned Lx = f2bf(sx - bf2f(Hx));
    const unsigned Ly = f2bf(sy - bf2f(Hy));
    const unsigned Lz = f2bf(sz - bf2f(Hz));
    const float n = fmaf(x, x, fmaf(y, y, z * z));
    const unsigned nh = f2bf(n), nl = f2bf(n - bf2f(nh));
    const unsigned one = 0x3F80u;
    uint4 w0, w1;
    w0.x = pk(Hx, Hy); w0.y = pk(Hz, Lx); w0.z = pk(Ly, Lz); w0.w = pk(Hx, Hy);
    w1.x = pk(Hz, nh); w1.y = pk(nl, one); w1.z = pk(one, 0u); w1.w = 0u;
    lds[(j >> 5) * 64 + (j & 31)]      = w0;  // half 0 (k 0..7)
    lds[(j >> 5) * 64 + 32 + (j & 31)] = w1;  // half 1 (k 8..15)
  }

  // --- build A fragments from raw points (row tiles t0, t0+1) ---
  // A k-vec: w0=[hx hy hz hx hy hz lx ly]  w1=[lz 1 1 nh nl 0 0 0]
  const float* P = d ? x2 : x1;
  const int t0 = rg * 16 + wave * 2;
  bf16x8 af[2];
#pragma unroll
  for (int rr = 0; rr < 2; ++rr) {
    const int r = (t0 + rr) * 32 + l31;
    const float* p = P + (size_t)(b * PTS + r) * 3;
    const float x = p[0], y = p[1], zc = p[2];
    const unsigned hx = f2bf(x), hy = f2bf(y), hz = f2bf(zc);
    const unsigned lx = f2bf(x - bf2f(hx));
    const unsigned ly = f2bf(y - bf2f(hy));
    const unsigned lz = f2bf(zc - bf2f(hz));
    const float n = fmaf(x, x, fmaf(y, y, zc * zc));
    const unsigned nh = f2bf(n), nl = f2bf(n - bf2f(nh));
    const unsigned one = 0x3F80u;
    uint4 w0, w1;
    w0.x = pk(hx, hy); w0.y = pk(hz, hx); w0.z = pk(hy, hz); w0.w = pk(lx, ly);
    w1.x = pk(lz, one); w1.y = pk(one, nh); w1.z = pk(nl, 0u); w1.w = 0u;
    uint4 w;
    w.x = half ? w1.x : w0.x; w.y = half ? w1.y : w0.y;
    w.z = half ? w1.z : w0.z; w.w = half ? w1.w : w0.w;
    af[rr] = *(const bf16x8*)&w;
  }
  const bf16x8 af0 = af[0], af1 = af[1];

  f32x16 zero;
#pragma unroll
  for (int e = 0; e < 16; ++e) zero[e] = 0.f;

  float rm0[16], rm1[16];
#pragma unroll
  for (int e = 0; e < 16; ++e) { rm0[e] = 3.0e38f; rm1[e] = 3.0e38f; }

  __syncthreads();  // panel staged (read-only afterwards: no more barriers)

  // --- phase-stagger (neutral, harmless; kept to match the measured best) ---
  for (int i = 0; i < wave; ++i) __builtin_amdgcn_s_sleep(2);

  // --- stream 64 tiles from LDS; 4-slot ring, 2 reads in flight ---
  const uint4* tp = &lds[half * 32 + l31];  // tile stride = 64 uint4
  bf16x8 buf[4];
  buf[0] = *(const bf16x8*)&tp[0];
  buf[1] = *(const bf16x8*)&tp[64];

#pragma unroll 2
  for (int g = 0; g < 32; ++g) {
    const int cur = (g & 1) * 2;
    const int nxt = ((g + 1) & 1) * 2;
    const int pf  = ((g + 1) & 31) * 2;  // wrap: last prefetch redundant, safe
    buf[nxt]     = *(const bf16x8*)&tp[pf * 64];
    buf[nxt + 1] = *(const bf16x8*)&tp[(pf + 1) * 64];
    const bf16x8 b0 = buf[cur], b1 = buf[cur + 1];
    const f32x16 a00 =
        __builtin_amdgcn_mfma_f32_32x32x16_bf16(af0, b0, zero, 0, 0, 0);
    const f32x16 a01 =
        __builtin_amdgcn_mfma_f32_32x32x16_bf16(af0, b1, zero, 0, 0, 0);
#pragma unroll
    for (int e = 0; e < 16; ++e)
      rm0[e] = fminf(fminf(a00[e], a01[e]), rm0[e]);  // v_min3_f32
    const f32x16 a10 =
        __builtin_amdgcn_mfma_f32_32x32x16_bf16(af1, b0, zero, 0, 0, 0);
    const f32x16 a11 =
        __builtin_amdgcn_mfma_f32_32x32x16_bf16(af1, b1, zero, 0, 0, 0);
#pragma unroll
    for (int e = 0; e < 16; ++e)
      rm1[e] = fminf(fminf(a10[e], a11[e]), rm1[e]);
  }

  // --- per-row min over this wave's 32 cols-per-half, direct store ---
  // C/D layout: col = lane&31, row_local = (e&3) + 8*(e>>2) + 4*half.
  // Each row written exactly once per col-half: no init, no atomics.
  float* rbase = rowpart + ((size_t)((ch * 2 + d) * NB + b)) * PTS + t0 * 32;
#pragma unroll
  for (int e = 0; e < 16; ++e) {
    float v = rm0[e];
    v = fminf(v, __shfl_xor(v, 1));
    v = fminf(v, __shfl_xor(v, 2));
    v = fminf(v, __shfl_xor(v, 4));
    v = fminf(v, __shfl_xor(v, 8));
    v = fminf(v, __shfl_xor(v, 16));
    if (l31 == e) {
      const int rl = (e & 3) + 8 * (e >> 2) + 4 * half;
      rbase[rl] = fmaxf(v, 0.f);
    }
  }
#pragma unroll
  for (int e = 0; e < 16; ++e) {
    float v = rm1[e];
    v = fminf(v, __shfl_xor(v, 1));
    v = fminf(v, __shfl_xor(v, 2));
    v = fminf(v, __shfl_xor(v, 4));
    v = fminf(v, __shfl_xor(v, 8));
    v = fminf(v, __shfl_xor(v, 16));
    if (l31 == e) {
      const int rl = 32 + (e & 3) + 8 * (e >> 2) + 4 * half;
      rbase[rl] = fmaxf(v, 0.f);
    }
  }
}

// ---- reduce: out[b] = mean_r min(ch0,ch1)[d=0] + mean_r min(ch0,ch1)[d=1] ----
// Planes: p = ch*2 + d -> d=0 in planes {0,2}, d=1 in planes {1,3}.
__global__ __launch_bounds__(512) void reduce_rows(
    const float* __restrict__ rowpart, float* __restrict__ out) {
  const int b = blockIdx.x;
  const int tid = threadIdx.x;
  const float* p0 = rowpart + (size_t)(0 * NB + b) * PTS;  // ch0,d0
  const float* p1 = rowpart + (size_t)(1 * NB + b) * PTS;  // ch0,d1
  const float* p2 = rowpart + (size_t)(2 * NB + b) * PTS;  // ch1,d0
  const float* p3 = rowpart + (size_t)(3 * NB + b) * PTS;  // ch1,d1
  float s = 0.f;
  for (int i = tid; i < PTS; i += 512)
    s += fminf(p0[i], p2[i]) + fminf(p1[i], p3[i]);
  s += __shfl_xor(s, 1);
  s += __shfl_xor(s, 2);
  s += __shfl_xor(s, 4);
  s += __shfl_xor(s, 8);
  s += __shfl_xor(s, 16);
  s += __shfl_xor(s, 32);
  __shared__ float acc[8];
  if ((tid & 63) == 0) acc[tid >> 6] = s;
  __syncthreads();
  if (tid == 0) {
    float t = 0.f;
#pragma unroll
    for (int w = 0; w < 8; ++w) t += acc[w];
    out[b] = t * (1.f / PTS);
  }
}

extern "C" void kernel_launch(void* const* d_in, const int* in_sizes, int n_in,
                              void* d_out, int out_size, void* d_ws,
                              size_t ws_size, hipStream_t stream) {
  const float* x1 = (const float*)d_in[0];
  const float* x2 = (const float*)d_in[1];
  float* out = (float*)d_out;

  float* rowpart = (float*)d_ws;  // 4*NB*PTS floats = 1 MB, fully overwritten

  dim3 grid(64, 8);  // x = (dir,b,ch) slice -> XCD = x%8 ; y = row-group
  chamfer_main<<<grid, 512, 0, stream>>>(x1, x2, rowpart);
  reduce_rows<<<NB, 512, 0, stream>>>(rowpart, out);
}